// Round 5
// baseline (311.444 us; speedup 1.0000x reference)
//
#include <hip/hip_runtime.h>
#include <hip/hip_cooperative_groups.h>
#include <math.h>

namespace cg = cooperative_groups;

#define NCLUS 64
#define BLOCK 256
#define GRID 1024            // 4 blocks/CU * 256 CUs; covers 1024*256*4 >= 1e6 points
#define FP_SCALE 1048576.0f  // 2^20 fixed-point scale for cluster sums

#if __has_builtin(__builtin_amdgcn_exp2f)
#define EXP2F(x) __builtin_amdgcn_exp2f(x)
#else
#define EXP2F(x) __expf(0.6931471805599453f * (x))
#endif

// softplus(p)=log(1+e^p) on [0,1] ~= Q0 + Q1*p + Q2*p^2 (Chebyshev-node quadratic),
// max err ~6e-4 (threshold is 26 on ~1304 -> irrelevant). Q0 hoisted to finalize.
#define SPQ0 0.692941
#define SPQ1 0.503668f
#define SPQ2 0.117225f

// ws layout (shared by both paths):
//  [0, 2560):        u64 S[320]  fixed-point cluster sums, idx = field*64+c
//                    field: 0=count 1=sx 2=sy 3=sz 4=margin
//  [2560, 4096):     float P[384] params (fallback path only)
//  [4096, 4096+GRID*12): float pb[GRID*3] per-block partials (bce,seed,smooth)

__device__ __forceinline__ float block_reduce_sum(float v, float* s_red) {
    for (int o = 32; o > 0; o >>= 1) v += __shfl_down(v, o);
    int lane = threadIdx.x & 63, wid = threadIdx.x >> 6;
    __syncthreads();
    if (lane == 0) s_red[wid] = v;
    __syncthreads();
    float t = 0.0f;
    if (threadIdx.x == 0)
        for (int w = 0; w < BLOCK / 64; ++w) t += s_red[w];
    return t;  // valid on thread 0 only
}

// ======================= fused cooperative kernel =======================

__global__ __launch_bounds__(BLOCK, 4) void fused_kernel(
        const float* __restrict__ emb, const float* __restrict__ margins,
        const float* __restrict__ seed, const float* __restrict__ coords,
        const int* __restrict__ labels, int n,
        unsigned long long* __restrict__ S, float* __restrict__ pb,
        float* __restrict__ out) {
    cg::grid_group grid = cg::this_grid();

    __shared__ float s_h[8][5][65];       // 8 replicas, padded
    __shared__ float4 s_par[NCLUS];       // ax,ay,az,b
    __shared__ float s_w[NCLUS];
    __shared__ float s_sig[NCLUS];
    __shared__ float s_red[BLOCK / 64];
    __shared__ double s_d[BLOCK / 64][3];

    const int tid = blockIdx.x * BLOCK + threadIdx.x;
    const int i0 = tid * 4;
    int nv = n - i0; nv = nv < 0 ? 0 : (nv > 4 ? 4 : nv);  // this thread's valid points

    // ---------- load the thread's 4 points into registers (read inputs ONCE) ----------
    float x[4], y[4], z[4], m[4], sd[4], qx[4], qy[4], qz[4];
    int l[4];
    if (nv == 4) {
        const float4* e4 = (const float4*)emb;
        const float4* c4 = (const float4*)coords;
        float4 e0 = e4[tid * 3], e1 = e4[tid * 3 + 1], e2 = e4[tid * 3 + 2];
        x[0] = e0.x; y[0] = e0.y; z[0] = e0.z; x[1] = e0.w; y[1] = e1.x; z[1] = e1.y;
        x[2] = e1.z; y[2] = e1.w; z[2] = e2.x; x[3] = e2.y; y[3] = e2.z; z[3] = e2.w;
        float4 q0 = c4[tid * 3], q1 = c4[tid * 3 + 1], q2 = c4[tid * 3 + 2];
        qx[0] = q0.x; qy[0] = q0.y; qz[0] = q0.z; qx[1] = q0.w; qy[1] = q1.x; qz[1] = q1.y;
        qx[2] = q1.z; qy[2] = q1.w; qz[2] = q2.x; qx[3] = q2.y; qy[3] = q2.z; qz[3] = q2.w;
        float4 mg = ((const float4*)margins)[tid];
        float4 sv = ((const float4*)seed)[tid];
        int4 lb = ((const int4*)labels)[tid];
        m[0] = mg.x; m[1] = mg.y; m[2] = mg.z; m[3] = mg.w;
        sd[0] = sv.x; sd[1] = sv.y; sd[2] = sv.z; sd[3] = sv.w;
        l[0] = lb.x; l[1] = lb.y; l[2] = lb.z; l[3] = lb.w;
    } else {
        for (int k = 0; k < 4; ++k) {
            int i = i0 + k;
            bool v = i < n;
            x[k]  = v ? emb[i * 3 + 0] : 0.f;
            y[k]  = v ? emb[i * 3 + 1] : 0.f;
            z[k]  = v ? emb[i * 3 + 2] : 0.f;
            qx[k] = v ? coords[i * 3 + 0] : 0.f;
            qy[k] = v ? coords[i * 3 + 1] : 0.f;
            qz[k] = v ? coords[i * 3 + 2] : 0.f;
            m[k]  = v ? margins[i] : 0.f;
            sd[k] = v ? seed[i] : 0.f;
            l[k]  = v ? labels[i] : 0;
        }
    }

    // ---------- P1: per-block LDS histogram of coords/margins ----------
    for (int i = threadIdx.x; i < 8 * 5 * 65; i += BLOCK) ((float*)s_h)[i] = 0.f;
    __syncthreads();
    const int rep = threadIdx.x & 7;
    for (int k = 0; k < nv; ++k) {
        atomicAdd(&s_h[rep][0][l[k]], 1.0f);
        atomicAdd(&s_h[rep][1][l[k]], qx[k]);
        atomicAdd(&s_h[rep][2][l[k]], qy[k]);
        atomicAdd(&s_h[rep][3][l[k]], qz[k]);
        atomicAdd(&s_h[rep][4][l[k]], m[k]);
    }
    // block 0 zeroes the global accumulator before anyone flushes (pre-sync)
    if (blockIdx.x == 0)
        for (int i = threadIdx.x; i < 5 * NCLUS; i += BLOCK) S[i] = 0ULL;
    __syncthreads();
    grid.sync();

    // flush LDS partials -> global u64 fixed-point (native int atomics)
    for (int idx = threadIdx.x; idx < 5 * NCLUS; idx += BLOCK) {
        int field = idx >> 6, c = idx & 63;
        float v = 0.f;
#pragma unroll
        for (int r = 0; r < 8; ++r) v += s_h[r][field][c];
        unsigned long long q = (unsigned long long)(long long)llrintf(v * FP_SCALE);
        if (q) atomicAdd(&S[idx], q);
    }
    grid.sync();

    // ---------- P2: every block derives params from S ----------
    if (threadIdx.x < NCLUS) {
        int c = threadIdx.x;
        const double inv_sc = 1.0 / (double)FP_SCALE;
        double cnt = (double)(long long)S[c] * inv_sc;
        double sx  = (double)(long long)S[64 + c] * inv_sc;
        double sy  = (double)(long long)S[128 + c] * inv_sc;
        double sz  = (double)(long long)S[192 + c] * inv_sc;
        double sm  = (double)(long long)S[256 + c] * inv_sc;
        double inv = 1.0 / cnt;
        double sig = sm * inv;
        double cx = sx * inv, cy = sy * inv, cz = sz * inv;
        double w2 = -1.4426950408889634 / (2.0 * sig * sig);
        s_par[c] = make_float4((float)(-2.0 * w2 * cx), (float)(-2.0 * w2 * cy),
                               (float)(-2.0 * w2 * cz),
                               (float)(w2 * (cx * cx + cy * cy + cz * cz)));
        s_w[c] = (float)w2;
        s_sig[c] = (float)sig;
    }
    __syncthreads();

    // ---------- P3: main loss over register-held points ----------
    float es[4], a[4] = {0.f, 0.f, 0.f, 0.f};
#pragma unroll
    for (int k = 0; k < 4; ++k)
        es[k] = fmaf(x[k], x[k], fmaf(y[k], y[k], z[k] * z[k]));

#pragma unroll 4
    for (int c = 0; c < NCLUS; ++c) {
        float4 pr = s_par[c];
        float w2 = s_w[c];
#pragma unroll
        for (int k = 0; k < 4; ++k) {
            float t = fmaf(pr.x, x[k],
                      fmaf(pr.y, y[k],
                      fmaf(pr.z, z[k],
                      fmaf(w2, es[k], pr.w))));
            float p = EXP2F(t);
            a[k] = fmaf(p, fmaf(p, SPQ2, SPQ1), a[k]);
        }
    }

    float bce = 0.f, seed_s = 0.f, smooth_s = 0.f;
    for (int k = 0; k < nv; ++k) bce += a[k];
    for (int k = 0; k < nv; ++k) {
        float4 pr = s_par[l[k]];
        float w2 = s_w[l[k]];
        float t = fmaf(pr.x, x[k],
                  fmaf(pr.y, y[k],
                  fmaf(pr.z, z[k],
                  fmaf(w2, es[k], pr.w))));
        float p = EXP2F(t);
        bce -= p;
        seed_s += fabsf(p - sd[k]);
        float dg = m[k] - s_sig[l[k]];
        smooth_s += dg * dg;
    }

    float r;
    r = block_reduce_sum(bce, s_red);
    if (threadIdx.x == 0) pb[blockIdx.x * 3 + 0] = r;
    r = block_reduce_sum(seed_s, s_red);
    if (threadIdx.x == 0) pb[blockIdx.x * 3 + 1] = r;
    r = block_reduce_sum(smooth_s, s_red);
    if (threadIdx.x == 0) pb[blockIdx.x * 3 + 2] = r;
    grid.sync();

    // ---------- P4: block 0 finalizes in double ----------
    if (blockIdx.x == 0) {
        double v0 = 0, v1 = 0, v2 = 0;
        for (int j = threadIdx.x; j < GRID; j += BLOCK) {
            v0 += (double)pb[j * 3 + 0];
            v1 += (double)pb[j * 3 + 1];
            v2 += (double)pb[j * 3 + 2];
        }
        for (int o = 32; o > 0; o >>= 1) {
            v0 += __shfl_down(v0, o); v1 += __shfl_down(v1, o); v2 += __shfl_down(v2, o);
        }
        int lane = threadIdx.x & 63, wid = threadIdx.x >> 6;
        if (lane == 0) { s_d[wid][0] = v0; s_d[wid][1] = v1; s_d[wid][2] = v2; }
        __syncthreads();
        if (threadIdx.x == 0) {
            double b = 0, se = 0, sm = 0;
            for (int w = 0; w < BLOCK / 64; ++w) {
                b += s_d[w][0]; se += s_d[w][1]; sm += s_d[w][2];
            }
            double bce_total = b + (double)n * 64.0 * SPQ0;
            out[0] = (float)(bce_total / ((double)NCLUS * (double)n)
                             + se / (double)n + sm / (double)NCLUS);
        }
    }
}

// ======================= fallback path (round-4, proven) =======================

__global__ void init_ws_kernel(unsigned long long* S) {
    int i = blockIdx.x * blockDim.x + threadIdx.x;
    if (i < 5 * NCLUS) S[i] = 0ULL;
}

__global__ __launch_bounds__(BLOCK) void cluster_sums_kernel(
        const float* __restrict__ coords, const float* __restrict__ margins,
        const int* __restrict__ labels, int n, unsigned long long* __restrict__ S) {
    __shared__ float s_h[8][5][65];
    for (int i = threadIdx.x; i < 8 * 5 * 65; i += blockDim.x)
        ((float*)s_h)[i] = 0.0f;
    __syncthreads();

    const int rep = threadIdx.x & 7;
    const int chunks = n >> 2;
    const int stride = gridDim.x * blockDim.x;
    const float4* c4 = (const float4*)coords;
    const float4* m4 = (const float4*)margins;
    const int4* l4 = (const int4*)labels;

    for (int ch = blockIdx.x * blockDim.x + threadIdx.x; ch < chunks; ch += stride) {
        float4 e0 = c4[ch * 3 + 0], e1 = c4[ch * 3 + 1], e2 = c4[ch * 3 + 2];
        float4 mg = m4[ch];
        int4 lb = l4[ch];
        float xx[4] = {e0.x, e0.w, e1.z, e2.y};
        float yy[4] = {e0.y, e1.x, e1.w, e2.z};
        float zz[4] = {e0.z, e1.y, e2.x, e2.w};
        float mm[4] = {mg.x, mg.y, mg.z, mg.w};
        int   ll[4] = {lb.x, lb.y, lb.z, lb.w};
#pragma unroll
        for (int k = 0; k < 4; ++k) {
            atomicAdd(&s_h[rep][0][ll[k]], 1.0f);
            atomicAdd(&s_h[rep][1][ll[k]], xx[k]);
            atomicAdd(&s_h[rep][2][ll[k]], yy[k]);
            atomicAdd(&s_h[rep][3][ll[k]], zz[k]);
            atomicAdd(&s_h[rep][4][ll[k]], mm[k]);
        }
    }
    int rem = n & 3;
    int gid = blockIdx.x * blockDim.x + threadIdx.x;
    if (gid < rem) {
        int i = ((n >> 2) << 2) + gid;
        int lab = labels[i];
        atomicAdd(&s_h[rep][0][lab], 1.0f);
        atomicAdd(&s_h[rep][1][lab], coords[i * 3 + 0]);
        atomicAdd(&s_h[rep][2][lab], coords[i * 3 + 1]);
        atomicAdd(&s_h[rep][3][lab], coords[i * 3 + 2]);
        atomicAdd(&s_h[rep][4][lab], margins[i]);
    }
    __syncthreads();
    for (int idx = threadIdx.x; idx < 5 * NCLUS; idx += blockDim.x) {
        int field = idx >> 6, c = idx & 63;
        float v = 0.0f;
#pragma unroll
        for (int r = 0; r < 8; ++r) v += s_h[r][field][c];
        unsigned long long q = (unsigned long long)(long long)llrintf(v * FP_SCALE);
        if (q) atomicAdd(&S[idx], q);
    }
}

__global__ void compute_params_kernel(const unsigned long long* __restrict__ S,
                                      float* __restrict__ P) {
    int c = threadIdx.x;
    if (c < NCLUS) {
        const double inv_sc = 1.0 / (double)FP_SCALE;
        double cnt = (double)(long long)S[c] * inv_sc;
        double sx  = (double)(long long)S[64 + c] * inv_sc;
        double sy  = (double)(long long)S[128 + c] * inv_sc;
        double sz  = (double)(long long)S[192 + c] * inv_sc;
        double sm  = (double)(long long)S[256 + c] * inv_sc;
        double inv = 1.0 / cnt;
        double sig = sm * inv;
        double cx = sx * inv, cy = sy * inv, cz = sz * inv;
        double w2 = -1.4426950408889634 / (2.0 * sig * sig);
        P[c * 4 + 0] = (float)(-2.0 * w2 * cx);
        P[c * 4 + 1] = (float)(-2.0 * w2 * cy);
        P[c * 4 + 2] = (float)(-2.0 * w2 * cz);
        P[c * 4 + 3] = (float)(w2 * (cx * cx + cy * cy + cz * cz));
        P[256 + c] = (float)w2;
        P[320 + c] = (float)sig;
    }
}

__global__ __launch_bounds__(BLOCK) void main_loss_kernel(
        const float* __restrict__ emb, const float* __restrict__ margins,
        const float* __restrict__ seed, const int* __restrict__ labels,
        int n, const float* __restrict__ P, float* __restrict__ pb) {
    __shared__ float4 s_par[NCLUS];
    __shared__ float s_w[NCLUS];
    __shared__ float s_sig[NCLUS];
    __shared__ float s_red[BLOCK / 64];

    if (threadIdx.x < NCLUS) {
        s_par[threadIdx.x] = ((const float4*)P)[threadIdx.x];
        s_w[threadIdx.x] = P[256 + threadIdx.x];
        s_sig[threadIdx.x] = P[320 + threadIdx.x];
    }
    __syncthreads();

    const int chunks = n >> 2;
    const int stride = gridDim.x * blockDim.x;
    const float4* e4 = (const float4*)emb;
    const float4* m4 = (const float4*)margins;
    const float4* s4 = (const float4*)seed;
    const int4* l4 = (const int4*)labels;

    float bce = 0.0f, seed_s = 0.0f, smooth_s = 0.0f;

    for (int ch = blockIdx.x * blockDim.x + threadIdx.x; ch < chunks; ch += stride) {
        float4 e0 = e4[ch * 3 + 0], e1 = e4[ch * 3 + 1], e2 = e4[ch * 3 + 2];
        float x[4] = {e0.x, e0.w, e1.z, e2.y};
        float y[4] = {e0.y, e1.x, e1.w, e2.z};
        float z[4] = {e0.z, e1.y, e2.x, e2.w};
        float es[4], a[4] = {0.f, 0.f, 0.f, 0.f};
#pragma unroll
        for (int k = 0; k < 4; ++k)
            es[k] = fmaf(x[k], x[k], fmaf(y[k], y[k], z[k] * z[k]));
#pragma unroll 4
        for (int c = 0; c < NCLUS; ++c) {
            float4 pr = s_par[c];
            float w2 = s_w[c];
#pragma unroll
            for (int k = 0; k < 4; ++k) {
                float t = fmaf(pr.x, x[k], fmaf(pr.y, y[k],
                          fmaf(pr.z, z[k], fmaf(w2, es[k], pr.w))));
                float p = EXP2F(t);
                a[k] = fmaf(p, fmaf(p, SPQ2, SPQ1), a[k]);
            }
        }
        bce += (a[0] + a[1]) + (a[2] + a[3]);

        float4 mg = m4[ch], sv = s4[ch];
        int4 lb = l4[ch];
        float mm[4] = {mg.x, mg.y, mg.z, mg.w};
        float ss[4] = {sv.x, sv.y, sv.z, sv.w};
        int   ll[4] = {lb.x, lb.y, lb.z, lb.w};
#pragma unroll
        for (int k = 0; k < 4; ++k) {
            float4 pr = s_par[ll[k]];
            float w2 = s_w[ll[k]];
            float t = fmaf(pr.x, x[k], fmaf(pr.y, y[k],
                      fmaf(pr.z, z[k], fmaf(w2, es[k], pr.w))));
            float p = EXP2F(t);
            bce -= p;
            seed_s += fabsf(p - ss[k]);
            float dg = mm[k] - s_sig[ll[k]];
            smooth_s += dg * dg;
        }
    }

    int covered = chunks << 2;
    int rem = n - covered;
    int gid = blockIdx.x * blockDim.x + threadIdx.x;
    if (gid < rem) {
        int i = covered + gid;
        float ex = emb[i * 3 + 0], ey = emb[i * 3 + 1], ez = emb[i * 3 + 2];
        float esq = fmaf(ex, ex, fmaf(ey, ey, ez * ez));
        int lab = labels[i];
        float pl = 0.0f;
        for (int c = 0; c < NCLUS; ++c) {
            float4 pr = s_par[c];
            float w2 = s_w[c];
            float t = fmaf(pr.x, ex, fmaf(pr.y, ey, fmaf(pr.z, ez, fmaf(w2, esq, pr.w))));
            float p = EXP2F(t);
            pl = (c == lab) ? p : pl;
            bce = fmaf(p, fmaf(p, SPQ2, SPQ1), bce);
        }
        bce -= pl;
        seed_s += fabsf(pl - seed[i]);
        float dg = margins[i] - s_sig[lab];
        smooth_s += dg * dg;
    }

    float r;
    r = block_reduce_sum(bce, s_red);
    if (threadIdx.x == 0) pb[blockIdx.x * 3 + 0] = r;
    r = block_reduce_sum(seed_s, s_red);
    if (threadIdx.x == 0) pb[blockIdx.x * 3 + 1] = r;
    r = block_reduce_sum(smooth_s, s_red);
    if (threadIdx.x == 0) pb[blockIdx.x * 3 + 2] = r;
}

__global__ void finalize_kernel(const float* __restrict__ pb, int nblocks,
                                float* __restrict__ out, int n) {
    int lane = threadIdx.x;
    double v0 = 0, v1 = 0, v2 = 0;
    for (int j = lane; j < nblocks; j += 64) {
        v0 += (double)pb[j * 3 + 0];
        v1 += (double)pb[j * 3 + 1];
        v2 += (double)pb[j * 3 + 2];
    }
    for (int o = 32; o > 0; o >>= 1) {
        v0 += __shfl_down(v0, o); v1 += __shfl_down(v1, o); v2 += __shfl_down(v2, o);
    }
    if (lane == 0) {
        double bce_total = v0 + (double)n * 64.0 * SPQ0;
        out[0] = (float)(bce_total / ((double)NCLUS * (double)n)
                         + v1 / (double)n + v2 / (double)NCLUS);
    }
}

// ======================= host launcher =======================

extern "C" void kernel_launch(void* const* d_in, const int* in_sizes, int n_in,
                              void* d_out, int out_size, void* d_ws, size_t ws_size,
                              hipStream_t stream) {
    const float* emb     = (const float*)d_in[0];
    const float* margins = (const float*)d_in[1];
    const float* seed    = (const float*)d_in[2];
    const float* coords  = (const float*)d_in[3];
    const int*   labels  = (const int*)d_in[4];
    int n = in_sizes[4];

    unsigned long long* S = (unsigned long long*)d_ws;
    float* P  = (float*)((char*)d_ws + 2560);
    float* pb = (float*)((char*)d_ws + 4096);
    float* out = (float*)d_out;

    hipError_t err = hipErrorUnknown;
    if (n <= GRID * BLOCK * 4) {
        void* args[9];
        args[0] = (void*)&emb;    args[1] = (void*)&margins;
        args[2] = (void*)&seed;   args[3] = (void*)&coords;
        args[4] = (void*)&labels; args[5] = (void*)&n;
        args[6] = (void*)&S;      args[7] = (void*)&pb;
        args[8] = (void*)&out;
        err = hipLaunchCooperativeKernel(reinterpret_cast<void*>(fused_kernel),
                                         dim3(GRID), dim3(BLOCK), args, 0, stream);
    }
    if (err != hipSuccess) {
        // fallback: proven 5-kernel path
        init_ws_kernel<<<1, 5 * NCLUS, 0, stream>>>(S);
        cluster_sums_kernel<<<512, BLOCK, 0, stream>>>(coords, margins, labels, n, S);
        compute_params_kernel<<<1, 64, 0, stream>>>(S, P);
        main_loss_kernel<<<1024, BLOCK, 0, stream>>>(emb, margins, seed, labels, n, P, pb);
        finalize_kernel<<<1, 64, 0, stream>>>(pb, 1024, out, n);
    }
}

// Round 6
// 101.626 us; speedup vs baseline: 3.0646x; 3.0646x over previous
//
#include <hip/hip_runtime.h>
#include <math.h>

#define NCLUS 64
#define BLOCK 256
#define MAXGRID 2048
#define FP_SCALE 1048576.0f  // 2^20 fixed-point scale for cluster sums

#if __has_builtin(__builtin_amdgcn_exp2f)
#define EXP2F(x) __builtin_amdgcn_exp2f(x)
#else
#define EXP2F(x) __expf(0.6931471805599453f * (x))
#endif

// softplus(p)=log(1+e^p) on [0,1] ~= Q0 + Q1*p + Q2*p^2, max err ~6e-4
// (irrelevant vs threshold). Q0 hoisted; added back at finalize as n*64*Q0.
#define SPQ0 0.692941
#define SPQ1 0.503668f
#define SPQ2 0.117225f

// ws layout:
//  [0, 2560):    u64 S[320]   fixed-point cluster sums, idx = field*64+c
//                field: 0=count 1=sx 2=sy 3=sz 4=margin
//  [2560, 2564): int counter  (last-block-done)
//  [4096, 4096+MAXGRID*12): float pb[grid*3]  per-block partials (bce,seed,smooth)

__global__ void init_ws_kernel(unsigned long long* S, int* counter) {
    int i = blockIdx.x * blockDim.x + threadIdx.x;
    if (i < 5 * NCLUS) S[i] = 0ULL;
    if (i == 0) *counter = 0;
}

__global__ __launch_bounds__(BLOCK) void cluster_sums_kernel(
        const float* __restrict__ coords, const float* __restrict__ margins,
        const int* __restrict__ labels, int n, unsigned long long* __restrict__ S) {
    __shared__ float s_h[8][5][65];   // 8 replicas, padded rows
    for (int i = threadIdx.x; i < 8 * 5 * 65; i += BLOCK)
        ((float*)s_h)[i] = 0.0f;
    __syncthreads();

    const int rep = threadIdx.x & 7;
    const int chunks = n >> 2;
    const int stride = gridDim.x * BLOCK;
    const float4* c4 = (const float4*)coords;
    const float4* m4 = (const float4*)margins;
    const int4* l4 = (const int4*)labels;

    for (int ch = blockIdx.x * BLOCK + threadIdx.x; ch < chunks; ch += stride) {
        float4 e0 = c4[ch * 3 + 0], e1 = c4[ch * 3 + 1], e2 = c4[ch * 3 + 2];
        float4 mg = m4[ch];
        int4 lb = l4[ch];
        float xx[4] = {e0.x, e0.w, e1.z, e2.y};
        float yy[4] = {e0.y, e1.x, e1.w, e2.z};
        float zz[4] = {e0.z, e1.y, e2.x, e2.w};
        float mm[4] = {mg.x, mg.y, mg.z, mg.w};
        int   ll[4] = {lb.x, lb.y, lb.z, lb.w};
#pragma unroll
        for (int k = 0; k < 4; ++k) {
            atomicAdd(&s_h[rep][0][ll[k]], 1.0f);
            atomicAdd(&s_h[rep][1][ll[k]], xx[k]);
            atomicAdd(&s_h[rep][2][ll[k]], yy[k]);
            atomicAdd(&s_h[rep][3][ll[k]], zz[k]);
            atomicAdd(&s_h[rep][4][ll[k]], mm[k]);
        }
    }
    // scalar tail
    int rem = n & 3;
    int gid = blockIdx.x * BLOCK + threadIdx.x;
    if (gid < rem) {
        int i = ((n >> 2) << 2) + gid;
        int lab = labels[i];
        atomicAdd(&s_h[rep][0][lab], 1.0f);
        atomicAdd(&s_h[rep][1][lab], coords[i * 3 + 0]);
        atomicAdd(&s_h[rep][2][lab], coords[i * 3 + 1]);
        atomicAdd(&s_h[rep][3][lab], coords[i * 3 + 2]);
        atomicAdd(&s_h[rep][4][lab], margins[i]);
    }
    __syncthreads();

    // flush: fixed-point u64 atomics (native int atomic, fire-and-forget)
    for (int idx = threadIdx.x; idx < 5 * NCLUS; idx += BLOCK) {
        int field = idx >> 6, c = idx & 63;
        float v = 0.0f;
#pragma unroll
        for (int r = 0; r < 8; ++r) v += s_h[r][field][c];
        unsigned long long q = (unsigned long long)(long long)llrintf(v * FP_SCALE);
        if (q) atomicAdd(&S[idx], q);
    }
}

__global__ __launch_bounds__(BLOCK) void main_loss_kernel(
        const float* __restrict__ emb, const float* __restrict__ margins,
        const float* __restrict__ seed, const int* __restrict__ labels,
        int n, const unsigned long long* __restrict__ S,
        float* __restrict__ pb, int* __restrict__ counter,
        float* __restrict__ out) {
    __shared__ float4 s_par[NCLUS];      // ax,ay,az,b
    __shared__ float4 s_w4[NCLUS / 4];   // w2 packed 4-wide
    __shared__ float s_sig[NCLUS];
    __shared__ float s_red[BLOCK / 64];
    __shared__ double s_d[BLOCK / 64][3];
    __shared__ int s_flag;

    // ---- params from S (every block; kernel boundary guarantees S visible) ----
    if (threadIdx.x < NCLUS) {
        int c = threadIdx.x;
        const double inv_sc = 1.0 / (double)FP_SCALE;
        double cnt = (double)(long long)S[c] * inv_sc;
        double sx  = (double)(long long)S[64 + c] * inv_sc;
        double sy  = (double)(long long)S[128 + c] * inv_sc;
        double sz  = (double)(long long)S[192 + c] * inv_sc;
        double sm  = (double)(long long)S[256 + c] * inv_sc;
        double inv = 1.0 / cnt;
        double sig = sm * inv;
        double cx = sx * inv, cy = sy * inv, cz = sz * inv;
        double w2 = -1.4426950408889634 / (2.0 * sig * sig);
        s_par[c] = make_float4((float)(-2.0 * w2 * cx), (float)(-2.0 * w2 * cy),
                               (float)(-2.0 * w2 * cz),
                               (float)(w2 * (cx * cx + cy * cy + cz * cz)));
        ((float*)s_w4)[c] = (float)w2;
        s_sig[c] = (float)sig;
    }
    __syncthreads();

    const int chunks = n >> 2;
    const int stride = gridDim.x * BLOCK;
    const float4* e4 = (const float4*)emb;
    const float4* m4 = (const float4*)margins;
    const float4* s4 = (const float4*)seed;
    const int4* l4 = (const int4*)labels;

    float bce = 0.0f, seed_s = 0.0f, smooth_s = 0.0f;

    for (int ch = blockIdx.x * BLOCK + threadIdx.x; ch < chunks; ch += stride) {
        float4 e0 = e4[ch * 3 + 0], e1 = e4[ch * 3 + 1], e2 = e4[ch * 3 + 2];
        float x[4] = {e0.x, e0.w, e1.z, e2.y};
        float y[4] = {e0.y, e1.x, e1.w, e2.z};
        float z[4] = {e0.z, e1.y, e2.x, e2.w};
        float es[4], a[4] = {0.f, 0.f, 0.f, 0.f};
#pragma unroll
        for (int k = 0; k < 4; ++k)
            es[k] = fmaf(x[k], x[k], fmaf(y[k], y[k], z[k] * z[k]));

#pragma unroll
        for (int c4i = 0; c4i < NCLUS / 4; ++c4i) {
            float4 wv = s_w4[c4i];
            float wa[4] = {wv.x, wv.y, wv.z, wv.w};
#pragma unroll
            for (int j = 0; j < 4; ++j) {
                float4 pr = s_par[c4i * 4 + j];
                float w2 = wa[j];
#pragma unroll
                for (int k = 0; k < 4; ++k) {
                    float t = fmaf(pr.x, x[k], fmaf(pr.y, y[k],
                              fmaf(pr.z, z[k], fmaf(w2, es[k], pr.w))));
                    float p = EXP2F(t);
                    a[k] = fmaf(p, fmaf(p, SPQ2, SPQ1), a[k]);
                }
            }
        }
        bce += (a[0] + a[1]) + (a[2] + a[3]);

        float4 mg = m4[ch], sv = s4[ch];
        int4 lb = l4[ch];
        float mm[4] = {mg.x, mg.y, mg.z, mg.w};
        float ss[4] = {sv.x, sv.y, sv.z, sv.w};
        int   ll[4] = {lb.x, lb.y, lb.z, lb.w};
#pragma unroll
        for (int k = 0; k < 4; ++k) {
            float4 pr = s_par[ll[k]];
            float w2 = ((const float*)s_w4)[ll[k]];
            float t = fmaf(pr.x, x[k], fmaf(pr.y, y[k],
                      fmaf(pr.z, z[k], fmaf(w2, es[k], pr.w))));
            float p = EXP2F(t);
            bce -= p;
            seed_s += fabsf(p - ss[k]);
            float dg = mm[k] - s_sig[ll[k]];
            smooth_s += dg * dg;
        }
    }

    // scalar tail
    int covered = chunks << 2;
    int rem = n - covered;
    int gid = blockIdx.x * BLOCK + threadIdx.x;
    if (gid < rem) {
        int i = covered + gid;
        float ex = emb[i * 3 + 0], ey = emb[i * 3 + 1], ez = emb[i * 3 + 2];
        float esq = fmaf(ex, ex, fmaf(ey, ey, ez * ez));
        int lab = labels[i];
        float pl = 0.0f;
        for (int c = 0; c < NCLUS; ++c) {
            float4 pr = s_par[c];
            float w2 = ((const float*)s_w4)[c];
            float t = fmaf(pr.x, ex, fmaf(pr.y, ey, fmaf(pr.z, ez, fmaf(w2, esq, pr.w))));
            float p = EXP2F(t);
            pl = (c == lab) ? p : pl;
            bce = fmaf(p, fmaf(p, SPQ2, SPQ1), bce);
        }
        bce -= pl;
        seed_s += fabsf(pl - seed[i]);
        float dg = margins[i] - s_sig[lab];
        smooth_s += dg * dg;
    }

    // ---- block partials ----
    float r;
    r = bce;
    for (int o = 32; o > 0; o >>= 1) r += __shfl_down(r, o);
    {
        int lane = threadIdx.x & 63, wid = threadIdx.x >> 6;
        __syncthreads();
        if (lane == 0) s_red[wid] = r;
        __syncthreads();
        if (threadIdx.x == 0) {
            float t = 0.f;
            for (int w = 0; w < BLOCK / 64; ++w) t += s_red[w];
            pb[blockIdx.x * 3 + 0] = t;
        }
    }
    r = seed_s;
    for (int o = 32; o > 0; o >>= 1) r += __shfl_down(r, o);
    {
        int lane = threadIdx.x & 63, wid = threadIdx.x >> 6;
        __syncthreads();
        if (lane == 0) s_red[wid] = r;
        __syncthreads();
        if (threadIdx.x == 0) {
            float t = 0.f;
            for (int w = 0; w < BLOCK / 64; ++w) t += s_red[w];
            pb[blockIdx.x * 3 + 1] = t;
        }
    }
    r = smooth_s;
    for (int o = 32; o > 0; o >>= 1) r += __shfl_down(r, o);
    {
        int lane = threadIdx.x & 63, wid = threadIdx.x >> 6;
        __syncthreads();
        if (lane == 0) s_red[wid] = r;
        __syncthreads();
        if (threadIdx.x == 0) {
            float t = 0.f;
            for (int w = 0; w < BLOCK / 64; ++w) t += s_red[w];
            pb[blockIdx.x * 3 + 2] = t;
        }
    }

    // ---- last-block-done finalize ----
    if (threadIdx.x == 0) {
        __threadfence();  // release our pb stores device-wide
        int old = __hip_atomic_fetch_add(counter, 1, __ATOMIC_ACQ_REL,
                                         __HIP_MEMORY_SCOPE_AGENT);
        s_flag = (old == (int)gridDim.x - 1) ? 1 : 0;
    }
    __syncthreads();
    if (s_flag) {
        __threadfence();  // acquire side
        double v0 = 0, v1 = 0, v2 = 0;
        int nb = gridDim.x;
        for (int j = threadIdx.x; j < nb; j += BLOCK) {
            v0 += (double)__hip_atomic_load(&pb[j * 3 + 0], __ATOMIC_RELAXED,
                                            __HIP_MEMORY_SCOPE_AGENT);
            v1 += (double)__hip_atomic_load(&pb[j * 3 + 1], __ATOMIC_RELAXED,
                                            __HIP_MEMORY_SCOPE_AGENT);
            v2 += (double)__hip_atomic_load(&pb[j * 3 + 2], __ATOMIC_RELAXED,
                                            __HIP_MEMORY_SCOPE_AGENT);
        }
        for (int o = 32; o > 0; o >>= 1) {
            v0 += __shfl_down(v0, o); v1 += __shfl_down(v1, o); v2 += __shfl_down(v2, o);
        }
        int lane = threadIdx.x & 63, wid = threadIdx.x >> 6;
        if (lane == 0) { s_d[wid][0] = v0; s_d[wid][1] = v1; s_d[wid][2] = v2; }
        __syncthreads();
        if (threadIdx.x == 0) {
            double b = 0, se = 0, sm = 0;
            for (int w = 0; w < BLOCK / 64; ++w) {
                b += s_d[w][0]; se += s_d[w][1]; sm += s_d[w][2];
            }
            double bce_total = b + (double)n * 64.0 * SPQ0;
            out[0] = (float)(bce_total / ((double)NCLUS * (double)n)
                             + se / (double)n + sm / (double)NCLUS);
        }
    }
}

extern "C" void kernel_launch(void* const* d_in, const int* in_sizes, int n_in,
                              void* d_out, int out_size, void* d_ws, size_t ws_size,
                              hipStream_t stream) {
    const float* emb     = (const float*)d_in[0];
    const float* margins = (const float*)d_in[1];
    const float* seed    = (const float*)d_in[2];
    const float* coords  = (const float*)d_in[3];
    const int*   labels  = (const int*)d_in[4];
    int n = in_sizes[4];

    unsigned long long* S = (unsigned long long*)d_ws;
    int* counter = (int*)((char*)d_ws + 2560);
    float* pb = (float*)((char*)d_ws + 4096);
    float* out = (float*)d_out;

    int chunks = n >> 2;
    int grid = (chunks + BLOCK - 1) / BLOCK;
    if (grid < 1) grid = 1;
    if (grid > MAXGRID) grid = MAXGRID;

    init_ws_kernel<<<1, 512, 0, stream>>>(S, counter);
    cluster_sums_kernel<<<grid, BLOCK, 0, stream>>>(coords, margins, labels, n, S);
    main_loss_kernel<<<grid, BLOCK, 0, stream>>>(emb, margins, seed, labels, n, S,
                                                 pb, counter, out);
}

// Round 7
// 89.377 us; speedup vs baseline: 3.4846x; 1.1370x over previous
//
#include <hip/hip_runtime.h>
#include <math.h>

#define NCLUS 64
#define BLOCK 256
#define MAXGRID 2048
#define FP_SCALE 1048576.0f  // 2^20 fixed-point scale for cluster sums

#if __has_builtin(__builtin_amdgcn_exp2f)
#define EXP2F(x) __builtin_amdgcn_exp2f(x)
#else
#define EXP2F(x) __expf(0.6931471805599453f * (x))
#endif

// softplus(p)=log(1+e^p) on [0,1] ~= Q0 + Q1*p + Q2*p^2, max err ~6e-4
// (irrelevant vs threshold). Q0 hoisted; added back at finalize as n*64*Q0.
#define SPQ0 0.692941
#define SPQ1 0.503668f
#define SPQ2 0.117225f

// ws layout:
//  [0, 2560):    u64 S[320]   fixed-point cluster sums, idx = field*64+c
//                field: 0=count 1=sx 2=sy 3=sz 4=margin
//  [2560, 2564): int counter  (last-block-done)
//  [4096, 4096+MAXGRID*12): float pb[grid*3]  per-block partials (bce,seed,smooth)

__global__ void init_ws_kernel(unsigned long long* S, int* counter) {
    int i = blockIdx.x * blockDim.x + threadIdx.x;
    if (i < 5 * NCLUS) S[i] = 0ULL;
    if (i == 0) *counter = 0;
}

__global__ __launch_bounds__(BLOCK) void cluster_sums_kernel(
        const float* __restrict__ coords, const float* __restrict__ margins,
        const int* __restrict__ labels, int n, unsigned long long* __restrict__ S) {
    __shared__ float s_h[8][5][65];   // 8 replicas, padded rows
    for (int i = threadIdx.x; i < 8 * 5 * 65; i += BLOCK)
        ((float*)s_h)[i] = 0.0f;
    __syncthreads();

    const int rep = threadIdx.x & 7;
    const int chunks = n >> 2;
    const int stride = gridDim.x * BLOCK;
    const float4* c4 = (const float4*)coords;
    const float4* m4 = (const float4*)margins;
    const int4* l4 = (const int4*)labels;

    for (int ch = blockIdx.x * BLOCK + threadIdx.x; ch < chunks; ch += stride) {
        float4 e0 = c4[ch * 3 + 0], e1 = c4[ch * 3 + 1], e2 = c4[ch * 3 + 2];
        float4 mg = m4[ch];
        int4 lb = l4[ch];
        float xx[4] = {e0.x, e0.w, e1.z, e2.y};
        float yy[4] = {e0.y, e1.x, e1.w, e2.z};
        float zz[4] = {e0.z, e1.y, e2.x, e2.w};
        float mm[4] = {mg.x, mg.y, mg.z, mg.w};
        int   ll[4] = {lb.x, lb.y, lb.z, lb.w};
#pragma unroll
        for (int k = 0; k < 4; ++k) {
            atomicAdd(&s_h[rep][0][ll[k]], 1.0f);
            atomicAdd(&s_h[rep][1][ll[k]], xx[k]);
            atomicAdd(&s_h[rep][2][ll[k]], yy[k]);
            atomicAdd(&s_h[rep][3][ll[k]], zz[k]);
            atomicAdd(&s_h[rep][4][ll[k]], mm[k]);
        }
    }
    // scalar tail
    int rem = n & 3;
    int gid = blockIdx.x * BLOCK + threadIdx.x;
    if (gid < rem) {
        int i = ((n >> 2) << 2) + gid;
        int lab = labels[i];
        atomicAdd(&s_h[rep][0][lab], 1.0f);
        atomicAdd(&s_h[rep][1][lab], coords[i * 3 + 0]);
        atomicAdd(&s_h[rep][2][lab], coords[i * 3 + 1]);
        atomicAdd(&s_h[rep][3][lab], coords[i * 3 + 2]);
        atomicAdd(&s_h[rep][4][lab], margins[i]);
    }
    __syncthreads();

    // flush: fixed-point u64 atomics (native int atomic, fire-and-forget)
    for (int idx = threadIdx.x; idx < 5 * NCLUS; idx += BLOCK) {
        int field = idx >> 6, c = idx & 63;
        float v = 0.0f;
#pragma unroll
        for (int r = 0; r < 8; ++r) v += s_h[r][field][c];
        unsigned long long q = (unsigned long long)(long long)llrintf(v * FP_SCALE);
        if (q) atomicAdd(&S[idx], q);
    }
}

// returns block sum on thread 0 only
__device__ __forceinline__ float block_reduce_f(float v, float* s_red) {
    for (int o = 32; o > 0; o >>= 1) v += __shfl_down(v, o);
    int lane = threadIdx.x & 63, wid = threadIdx.x >> 6;
    __syncthreads();
    if (lane == 0) s_red[wid] = v;
    __syncthreads();
    float t = 0.0f;
    if (threadIdx.x == 0)
        for (int w = 0; w < BLOCK / 64; ++w) t += s_red[w];
    return t;
}

__global__ __launch_bounds__(BLOCK, 4) void main_loss_kernel(
        const float* __restrict__ emb, const float* __restrict__ margins,
        const float* __restrict__ seed, const int* __restrict__ labels,
        int n, const unsigned long long* __restrict__ S,
        float* __restrict__ pb, int* __restrict__ counter,
        float* __restrict__ out) {
    __shared__ float4 s_par[NCLUS];   // ax,ay,az,b
    __shared__ float s_w[NCLUS];
    __shared__ float s_sig[NCLUS];
    __shared__ float s_red[BLOCK / 64];
    __shared__ int s_flag;

    // ---- params from S, all-float (2^20 scale cancels in every ratio) ----
    if (threadIdx.x < NCLUS) {
        int c = threadIdx.x;
        float cnt = (float)(long long)S[c];
        float sx  = (float)(long long)S[64 + c];
        float sy  = (float)(long long)S[128 + c];
        float sz  = (float)(long long)S[192 + c];
        float sm  = (float)(long long)S[256 + c];
        float inv = 1.0f / cnt;
        float sig = sm * inv;
        float cx = sx * inv, cy = sy * inv, cz = sz * inv;
        float w2 = -1.4426950408889634f / (2.0f * sig * sig);
        s_par[c] = make_float4(-2.0f * w2 * cx, -2.0f * w2 * cy, -2.0f * w2 * cz,
                               w2 * fmaf(cx, cx, fmaf(cy, cy, cz * cz)));
        s_w[c] = w2;
        s_sig[c] = sig;
    }
    __syncthreads();

    const int chunks = n >> 2;
    const int stride = gridDim.x * BLOCK;
    const float4* e4 = (const float4*)emb;
    const float4* m4 = (const float4*)margins;
    const float4* s4 = (const float4*)seed;
    const int4* l4 = (const int4*)labels;

    float bce = 0.0f, seed_s = 0.0f, smooth_s = 0.0f;

    for (int ch = blockIdx.x * BLOCK + threadIdx.x; ch < chunks; ch += stride) {
        float4 e0 = e4[ch * 3 + 0], e1 = e4[ch * 3 + 1], e2 = e4[ch * 3 + 2];
        float x[4] = {e0.x, e0.w, e1.z, e2.y};
        float y[4] = {e0.y, e1.x, e1.w, e2.z};
        float z[4] = {e0.z, e1.y, e2.x, e2.w};
        float es[4], a[4] = {0.f, 0.f, 0.f, 0.f};
#pragma unroll
        for (int k = 0; k < 4; ++k)
            es[k] = fmaf(x[k], x[k], fmaf(y[k], y[k], z[k] * z[k]));

#pragma unroll 4
        for (int c = 0; c < NCLUS; ++c) {
            float4 pr = s_par[c];
            float w2 = s_w[c];
#pragma unroll
            for (int k = 0; k < 4; ++k) {
                float t = fmaf(pr.x, x[k], fmaf(pr.y, y[k],
                          fmaf(pr.z, z[k], fmaf(w2, es[k], pr.w))));
                float p = EXP2F(t);
                a[k] = fmaf(p, fmaf(p, SPQ2, SPQ1), a[k]);
            }
        }
        bce += (a[0] + a[1]) + (a[2] + a[3]);

        float4 mg = m4[ch], sv = s4[ch];
        int4 lb = l4[ch];
        float mm[4] = {mg.x, mg.y, mg.z, mg.w};
        float ss[4] = {sv.x, sv.y, sv.z, sv.w};
        int   ll[4] = {lb.x, lb.y, lb.z, lb.w};
#pragma unroll
        for (int k = 0; k < 4; ++k) {
            float4 pr = s_par[ll[k]];
            float w2 = s_w[ll[k]];
            float t = fmaf(pr.x, x[k], fmaf(pr.y, y[k],
                      fmaf(pr.z, z[k], fmaf(w2, es[k], pr.w))));
            float p = EXP2F(t);
            bce -= p;
            seed_s += fabsf(p - ss[k]);
            float dg = mm[k] - s_sig[ll[k]];
            smooth_s += dg * dg;
        }
    }

    // scalar tail
    int covered = chunks << 2;
    int rem = n - covered;
    int gid = blockIdx.x * BLOCK + threadIdx.x;
    if (gid < rem) {
        int i = covered + gid;
        float ex = emb[i * 3 + 0], ey = emb[i * 3 + 1], ez = emb[i * 3 + 2];
        float esq = fmaf(ex, ex, fmaf(ey, ey, ez * ez));
        int lab = labels[i];
        float pl = 0.0f;
        for (int c = 0; c < NCLUS; ++c) {
            float4 pr = s_par[c];
            float w2 = s_w[c];
            float t = fmaf(pr.x, ex, fmaf(pr.y, ey, fmaf(pr.z, ez, fmaf(w2, esq, pr.w))));
            float p = EXP2F(t);
            pl = (c == lab) ? p : pl;
            bce = fmaf(p, fmaf(p, SPQ2, SPQ1), bce);
        }
        bce -= pl;
        seed_s += fabsf(pl - seed[i]);
        float dg = margins[i] - s_sig[lab];
        smooth_s += dg * dg;
    }

    // ---- block partials (float) ----
    float r;
    r = block_reduce_f(bce, s_red);
    if (threadIdx.x == 0) pb[blockIdx.x * 3 + 0] = r;
    r = block_reduce_f(seed_s, s_red);
    if (threadIdx.x == 0) pb[blockIdx.x * 3 + 1] = r;
    r = block_reduce_f(smooth_s, s_red);
    if (threadIdx.x == 0) pb[blockIdx.x * 3 + 2] = r;

    // ---- last-block-done finalize (float partials, double only in last 5 ops) ----
    if (threadIdx.x == 0) {
        __threadfence();  // release pb stores device-wide
        int old = __hip_atomic_fetch_add(counter, 1, __ATOMIC_ACQ_REL,
                                         __HIP_MEMORY_SCOPE_AGENT);
        s_flag = (old == (int)gridDim.x - 1) ? 1 : 0;
    }
    __syncthreads();
    if (s_flag) {
        __threadfence();  // acquire side
        int nb = gridDim.x;
        float v0 = 0.f, v1 = 0.f, v2 = 0.f;
        for (int j = threadIdx.x; j < nb; j += BLOCK) {
            v0 += __hip_atomic_load(&pb[j * 3 + 0], __ATOMIC_RELAXED,
                                    __HIP_MEMORY_SCOPE_AGENT);
            v1 += __hip_atomic_load(&pb[j * 3 + 1], __ATOMIC_RELAXED,
                                    __HIP_MEMORY_SCOPE_AGENT);
            v2 += __hip_atomic_load(&pb[j * 3 + 2], __ATOMIC_RELAXED,
                                    __HIP_MEMORY_SCOPE_AGENT);
        }
        float t0 = block_reduce_f(v0, s_red);
        float t1 = block_reduce_f(v1, s_red);
        float t2 = block_reduce_f(v2, s_red);
        if (threadIdx.x == 0) {
            double bce_total = (double)t0 + (double)n * 64.0 * SPQ0;
            out[0] = (float)(bce_total / ((double)NCLUS * (double)n)
                             + (double)t1 / (double)n + (double)t2 / (double)NCLUS);
        }
    }
}

extern "C" void kernel_launch(void* const* d_in, const int* in_sizes, int n_in,
                              void* d_out, int out_size, void* d_ws, size_t ws_size,
                              hipStream_t stream) {
    const float* emb     = (const float*)d_in[0];
    const float* margins = (const float*)d_in[1];
    const float* seed    = (const float*)d_in[2];
    const float* coords  = (const float*)d_in[3];
    const int*   labels  = (const int*)d_in[4];
    int n = in_sizes[4];

    unsigned long long* S = (unsigned long long*)d_ws;
    int* counter = (int*)((char*)d_ws + 2560);
    float* pb = (float*)((char*)d_ws + 4096);
    float* out = (float*)d_out;

    int chunks = n >> 2;
    int grid = (chunks + BLOCK - 1) / BLOCK;
    if (grid < 1) grid = 1;
    if (grid > MAXGRID) grid = MAXGRID;

    init_ws_kernel<<<1, 512, 0, stream>>>(S, counter);
    cluster_sums_kernel<<<grid, BLOCK, 0, stream>>>(coords, margins, labels, n, S);
    main_loss_kernel<<<grid, BLOCK, 0, stream>>>(emb, margins, seed, labels, n, S,
                                                 pb, counter, out);
}

// Round 8
// 85.606 us; speedup vs baseline: 3.6381x; 1.0440x over previous
//
#include <hip/hip_runtime.h>
#include <math.h>

#define NCLUS 64
#define BLOCK 256
#define FP_SCALE 1048576.0f  // 2^20 fixed-point scale for cluster sums

#if __has_builtin(__builtin_amdgcn_exp2f)
#define EXP2F(x) __builtin_amdgcn_exp2f(x)
#else
#define EXP2F(x) __expf(0.6931471805599453f * (x))
#endif

// softplus(p)=log(1+e^p) on [0,1] ~= Q0 + Q1*p + Q2*p^2, max err ~6e-4
// (irrelevant vs threshold). Q0 hoisted; added back at finalize as n*64*Q0.
#define SPQ0 0.692941
#define SPQ1 0.503668f
#define SPQ2 0.117225f

// ws layout:
//  [0, 2560):    u64 S[320]  fixed-point cluster sums, idx = field*64+c
//                field: 0=count 1=sx 2=sy 3=sz 4=margin
//  [4096, ...):  float pb[grid*3]  per-block partials (bce,seed,smooth)

__global__ void init_ws_kernel(unsigned long long* S) {
    int i = threadIdx.x;
    if (i < 5 * NCLUS) S[i] = 0ULL;
}

// 2 points per thread; grid covers all pairs exactly (no grid-stride loop).
__global__ __launch_bounds__(BLOCK) void cluster_sums_kernel(
        const float* __restrict__ coords, const float* __restrict__ margins,
        const int* __restrict__ labels, int n, unsigned long long* __restrict__ S) {
    __shared__ float s_h[8][5][65];   // 8 replicas, padded rows
    for (int i = threadIdx.x; i < 8 * 5 * 65; i += BLOCK)
        ((float*)s_h)[i] = 0.0f;
    __syncthreads();

    const int rep = threadIdx.x & 7;
    const int np = n >> 1;
    const int i = blockIdx.x * BLOCK + threadIdx.x;  // pair index

    if (i < np) {
        const float2* c2 = (const float2*)coords;
        float2 a0 = c2[i * 3], a1 = c2[i * 3 + 1], a2 = c2[i * 3 + 2];
        float2 mg = ((const float2*)margins)[i];
        int2 lb = ((const int2*)labels)[i];
        // point 0: (a0.x, a0.y, a1.x), point 1: (a1.y, a2.x, a2.y)
        atomicAdd(&s_h[rep][0][lb.x], 1.0f);
        atomicAdd(&s_h[rep][1][lb.x], a0.x);
        atomicAdd(&s_h[rep][2][lb.x], a0.y);
        atomicAdd(&s_h[rep][3][lb.x], a1.x);
        atomicAdd(&s_h[rep][4][lb.x], mg.x);
        atomicAdd(&s_h[rep][0][lb.y], 1.0f);
        atomicAdd(&s_h[rep][1][lb.y], a1.y);
        atomicAdd(&s_h[rep][2][lb.y], a2.x);
        atomicAdd(&s_h[rep][3][lb.y], a2.y);
        atomicAdd(&s_h[rep][4][lb.y], mg.y);
    }
    // odd-n tail: global thread 0 handles the last point
    if ((n & 1) && blockIdx.x == 0 && threadIdx.x == 0) {
        int p = n - 1;
        int lab = labels[p];
        atomicAdd(&s_h[rep][0][lab], 1.0f);
        atomicAdd(&s_h[rep][1][lab], coords[p * 3 + 0]);
        atomicAdd(&s_h[rep][2][lab], coords[p * 3 + 1]);
        atomicAdd(&s_h[rep][3][lab], coords[p * 3 + 2]);
        atomicAdd(&s_h[rep][4][lab], margins[p]);
    }
    __syncthreads();

    // flush: fixed-point u64 atomics (native int atomic, fire-and-forget)
    for (int idx = threadIdx.x; idx < 5 * NCLUS; idx += BLOCK) {
        int field = idx >> 6, c = idx & 63;
        float v = 0.0f;
#pragma unroll
        for (int r = 0; r < 8; ++r) v += s_h[r][field][c];
        unsigned long long q = (unsigned long long)(long long)llrintf(v * FP_SCALE);
        if (q) atomicAdd(&S[idx], q);
    }
}

// returns block sum on thread 0 only
__device__ __forceinline__ float block_reduce_f(float v, float* s_red) {
    for (int o = 32; o > 0; o >>= 1) v += __shfl_down(v, o);
    int lane = threadIdx.x & 63, wid = threadIdx.x >> 6;
    __syncthreads();
    if (lane == 0) s_red[wid] = v;
    __syncthreads();
    float t = 0.0f;
    if (threadIdx.x == 0)
        for (int w = 0; w < BLOCK / 64; ++w) t += s_red[w];
    return t;
}

__global__ __launch_bounds__(BLOCK, 8) void main_loss_kernel(
        const float* __restrict__ emb, const float* __restrict__ margins,
        const float* __restrict__ seed, const int* __restrict__ labels,
        int n, const unsigned long long* __restrict__ S,
        float* __restrict__ pb) {
    __shared__ float4 s_par[NCLUS];   // ax,ay,az,b
    __shared__ float s_w[NCLUS];
    __shared__ float s_sig[NCLUS];
    __shared__ float s_red[BLOCK / 64];

    // ---- params from S, all-float (2^20 scale cancels in every ratio) ----
    if (threadIdx.x < NCLUS) {
        int c = threadIdx.x;
        float cnt = (float)(long long)S[c];
        float sx  = (float)(long long)S[64 + c];
        float sy  = (float)(long long)S[128 + c];
        float sz  = (float)(long long)S[192 + c];
        float sm  = (float)(long long)S[256 + c];
        float inv = 1.0f / cnt;
        float sig = sm * inv;
        float cx = sx * inv, cy = sy * inv, cz = sz * inv;
        float w2 = -1.4426950408889634f / (2.0f * sig * sig);
        s_par[c] = make_float4(-2.0f * w2 * cx, -2.0f * w2 * cy, -2.0f * w2 * cz,
                               w2 * fmaf(cx, cx, fmaf(cy, cy, cz * cz)));
        s_w[c] = w2;
        s_sig[c] = sig;
    }
    __syncthreads();

    const int np = n >> 1;
    const int i = blockIdx.x * BLOCK + threadIdx.x;  // pair index

    float bce = 0.0f, seed_s = 0.0f, smooth_s = 0.0f;

    if (i < np) {
        // issue ALL global loads up front
        const float2* e2 = (const float2*)emb;
        float2 a0 = e2[i * 3], a1 = e2[i * 3 + 1], a2 = e2[i * 3 + 2];
        float2 mg = ((const float2*)margins)[i];
        float2 sv = ((const float2*)seed)[i];
        int2 lb = ((const int2*)labels)[i];

        float x[2] = {a0.x, a1.y};
        float y[2] = {a0.y, a2.x};
        float z[2] = {a1.x, a2.y};
        float es[2], a[2] = {0.f, 0.f};
#pragma unroll
        for (int k = 0; k < 2; ++k)
            es[k] = fmaf(x[k], x[k], fmaf(y[k], y[k], z[k] * z[k]));

#pragma unroll 8
        for (int c = 0; c < NCLUS; ++c) {
            float4 pr = s_par[c];
            float w2 = s_w[c];
#pragma unroll
            for (int k = 0; k < 2; ++k) {
                float t = fmaf(pr.x, x[k], fmaf(pr.y, y[k],
                          fmaf(pr.z, z[k], fmaf(w2, es[k], pr.w))));
                float p = EXP2F(t);
                a[k] = fmaf(p, fmaf(p, SPQ2, SPQ1), a[k]);
            }
        }
        bce += a[0] + a[1];

        float mm[2] = {mg.x, mg.y};
        float ss[2] = {sv.x, sv.y};
        int   ll[2] = {lb.x, lb.y};
#pragma unroll
        for (int k = 0; k < 2; ++k) {
            float4 pr = s_par[ll[k]];
            float w2 = s_w[ll[k]];
            float t = fmaf(pr.x, x[k], fmaf(pr.y, y[k],
                      fmaf(pr.z, z[k], fmaf(w2, es[k], pr.w))));
            float p = EXP2F(t);
            bce -= p;
            seed_s += fabsf(p - ss[k]);
            float dg = mm[k] - s_sig[ll[k]];
            smooth_s += dg * dg;
        }
    }
    // odd-n tail
    if ((n & 1) && blockIdx.x == 0 && threadIdx.x == 0) {
        int p = n - 1;
        float ex = emb[p * 3 + 0], ey = emb[p * 3 + 1], ez = emb[p * 3 + 2];
        float esq = fmaf(ex, ex, fmaf(ey, ey, ez * ez));
        int lab = labels[p];
        float pl = 0.0f;
        for (int c = 0; c < NCLUS; ++c) {
            float4 pr = s_par[c];
            float w2 = s_w[c];
            float t = fmaf(pr.x, ex, fmaf(pr.y, ey, fmaf(pr.z, ez, fmaf(w2, esq, pr.w))));
            float p2 = EXP2F(t);
            pl = (c == lab) ? p2 : pl;
            bce = fmaf(p2, fmaf(p2, SPQ2, SPQ1), bce);
        }
        bce -= pl;
        seed_s += fabsf(pl - seed[p]);
        float dg = margins[p] - s_sig[lab];
        smooth_s += dg * dg;
    }

    float r;
    r = block_reduce_f(bce, s_red);
    if (threadIdx.x == 0) pb[blockIdx.x * 3 + 0] = r;
    r = block_reduce_f(seed_s, s_red);
    if (threadIdx.x == 0) pb[blockIdx.x * 3 + 1] = r;
    r = block_reduce_f(smooth_s, s_red);
    if (threadIdx.x == 0) pb[blockIdx.x * 3 + 2] = r;
}

__global__ void finalize_kernel(const float* __restrict__ pb, int nb,
                                float* __restrict__ out, int n) {
    __shared__ float s_red[BLOCK / 64];
    float v0 = 0.f, v1 = 0.f, v2 = 0.f;
    for (int j = threadIdx.x; j < nb; j += BLOCK) {
        v0 += pb[j * 3 + 0];
        v1 += pb[j * 3 + 1];
        v2 += pb[j * 3 + 2];
    }
    float t0 = block_reduce_f(v0, s_red);
    __syncthreads();
    float t1 = block_reduce_f(v1, s_red);
    __syncthreads();
    float t2 = block_reduce_f(v2, s_red);
    if (threadIdx.x == 0) {
        double bce_total = (double)t0 + (double)n * 64.0 * SPQ0;
        out[0] = (float)(bce_total / ((double)NCLUS * (double)n)
                         + (double)t1 / (double)n + (double)t2 / (double)NCLUS);
    }
}

extern "C" void kernel_launch(void* const* d_in, const int* in_sizes, int n_in,
                              void* d_out, int out_size, void* d_ws, size_t ws_size,
                              hipStream_t stream) {
    const float* emb     = (const float*)d_in[0];
    const float* margins = (const float*)d_in[1];
    const float* seed    = (const float*)d_in[2];
    const float* coords  = (const float*)d_in[3];
    const int*   labels  = (const int*)d_in[4];
    int n = in_sizes[4];

    unsigned long long* S = (unsigned long long*)d_ws;
    float* pb = (float*)((char*)d_ws + 4096);
    float* out = (float*)d_out;

    int np = n >> 1;
    int grid = (np + BLOCK - 1) / BLOCK;
    if (grid < 1) grid = 1;

    init_ws_kernel<<<1, 512, 0, stream>>>(S);
    cluster_sums_kernel<<<grid, BLOCK, 0, stream>>>(coords, margins, labels, n, S);
    main_loss_kernel<<<grid, BLOCK, 0, stream>>>(emb, margins, seed, labels, n, S, pb);
    finalize_kernel<<<1, BLOCK, 0, stream>>>(pb, grid, out, n);
}

// Round 9
// 59.384 us; speedup vs baseline: 5.2446x; 1.4416x over previous
//
#include <hip/hip_runtime.h>
#include <math.h>

#define NCLUS 64
#define BLOCK 256
#define GC 512               // cluster_sums grid (grid-stride)
#define NREP 8               // global S replicas to spread atomic contention
#define FP_SCALE 1048576.0f  // 2^20 fixed-point scale for cluster sums

#if __has_builtin(__builtin_amdgcn_exp2f)
#define EXP2F(x) __builtin_amdgcn_exp2f(x)
#else
#define EXP2F(x) __expf(0.6931471805599453f * (x))
#endif

// softplus(p)=log(1+e^p) on [0,1] ~= Q0 + Q1*p + Q2*p^2, max err ~6e-4
// (irrelevant vs threshold). Q0 hoisted; added back at finalize as n*64*Q0.
#define SPQ0 0.692941
#define SPQ1 0.503668f
#define SPQ2 0.117225f

// ws layout:
//  [0, 20480):   u64 S8[8][320]  fixed-point cluster sums, idx = field*64+c
//                field: 0=count 1=sx 2=sy 3=sz 4=margin; replica = blockIdx&7
//  [24576, ...): float pb[grid*3]  per-block partials (bce,seed,smooth)

__global__ void init_ws_kernel(unsigned long long* S8) {
    int i = blockIdx.x * blockDim.x + threadIdx.x;
    if (i < NREP * 5 * NCLUS) S8[i] = 0ULL;
}

__global__ __launch_bounds__(BLOCK) void cluster_sums_kernel(
        const float* __restrict__ coords, const float* __restrict__ margins,
        const int* __restrict__ labels, int n, unsigned long long* __restrict__ S8) {
    __shared__ float s_h[8][5][65];   // 8 LDS replicas, padded rows
    for (int i = threadIdx.x; i < 8 * 5 * 65; i += BLOCK)
        ((float*)s_h)[i] = 0.0f;
    __syncthreads();

    const int rep = threadIdx.x & 7;
    const int np = n >> 1;
    const int stride = gridDim.x * BLOCK;
    const float2* c2 = (const float2*)coords;
    const float2* m2 = (const float2*)margins;
    const int2* l2 = (const int2*)labels;

    for (int i = blockIdx.x * BLOCK + threadIdx.x; i < np; i += stride) {
        float2 a0 = c2[i * 3], a1 = c2[i * 3 + 1], a2 = c2[i * 3 + 2];
        float2 mg = m2[i];
        int2 lb = l2[i];
        // point 0: (a0.x, a0.y, a1.x), point 1: (a1.y, a2.x, a2.y)
        atomicAdd(&s_h[rep][0][lb.x], 1.0f);
        atomicAdd(&s_h[rep][1][lb.x], a0.x);
        atomicAdd(&s_h[rep][2][lb.x], a0.y);
        atomicAdd(&s_h[rep][3][lb.x], a1.x);
        atomicAdd(&s_h[rep][4][lb.x], mg.x);
        atomicAdd(&s_h[rep][0][lb.y], 1.0f);
        atomicAdd(&s_h[rep][1][lb.y], a1.y);
        atomicAdd(&s_h[rep][2][lb.y], a2.x);
        atomicAdd(&s_h[rep][3][lb.y], a2.y);
        atomicAdd(&s_h[rep][4][lb.y], mg.y);
    }
    // odd-n tail
    if ((n & 1) && blockIdx.x == 0 && threadIdx.x == 0) {
        int p = n - 1;
        int lab = labels[p];
        atomicAdd(&s_h[rep][0][lab], 1.0f);
        atomicAdd(&s_h[rep][1][lab], coords[p * 3 + 0]);
        atomicAdd(&s_h[rep][2][lab], coords[p * 3 + 1]);
        atomicAdd(&s_h[rep][3][lab], coords[p * 3 + 2]);
        atomicAdd(&s_h[rep][4][lab], margins[p]);
    }
    __syncthreads();

    // flush to the block's global replica: u64 fixed-point, native int atomics,
    // spread over NREP*320 addresses to cut per-cache-line contention
    unsigned long long* Sr = S8 + (blockIdx.x & (NREP - 1)) * 5 * NCLUS;
    for (int idx = threadIdx.x; idx < 5 * NCLUS; idx += BLOCK) {
        int field = idx >> 6, c = idx & 63;
        float v = 0.0f;
#pragma unroll
        for (int r = 0; r < 8; ++r) v += s_h[r][field][c];
        unsigned long long q = (unsigned long long)(long long)llrintf(v * FP_SCALE);
        if (q) atomicAdd(&Sr[idx], q);
    }
}

// returns block sum on thread 0 only
__device__ __forceinline__ float block_reduce_f(float v, float* s_red) {
    for (int o = 32; o > 0; o >>= 1) v += __shfl_down(v, o);
    int lane = threadIdx.x & 63, wid = threadIdx.x >> 6;
    __syncthreads();
    if (lane == 0) s_red[wid] = v;
    __syncthreads();
    float t = 0.0f;
    if (threadIdx.x == 0)
        for (int w = 0; w < BLOCK / 64; ++w) t += s_red[w];
    return t;
}

__global__ __launch_bounds__(BLOCK, 8) void main_loss_kernel(
        const float* __restrict__ emb, const float* __restrict__ margins,
        const float* __restrict__ seed, const int* __restrict__ labels,
        int n, const unsigned long long* __restrict__ S8,
        float* __restrict__ pb) {
    __shared__ float4 s_par[NCLUS];   // ax,ay,az,b
    __shared__ float s_w[NCLUS];
    __shared__ float s_sig[NCLUS];
    __shared__ float s_red[BLOCK / 64];

    // ---- params: sum NREP replicas, all-float after (2^20 scale cancels) ----
    if (threadIdx.x < NCLUS) {
        int c = threadIdx.x;
        long long acc[5] = {0, 0, 0, 0, 0};
#pragma unroll
        for (int r = 0; r < NREP; ++r) {
#pragma unroll
            for (int f = 0; f < 5; ++f)
                acc[f] += (long long)S8[r * 5 * NCLUS + f * NCLUS + c];
        }
        float cnt = (float)acc[0];
        float sx = (float)acc[1], sy = (float)acc[2], sz = (float)acc[3];
        float sm = (float)acc[4];
        float inv = 1.0f / cnt;
        float sig = sm * inv;
        float cx = sx * inv, cy = sy * inv, cz = sz * inv;
        float w2 = -1.4426950408889634f / (2.0f * sig * sig);
        s_par[c] = make_float4(-2.0f * w2 * cx, -2.0f * w2 * cy, -2.0f * w2 * cz,
                               w2 * fmaf(cx, cx, fmaf(cy, cy, cz * cz)));
        s_w[c] = w2;
        s_sig[c] = sig;
    }
    __syncthreads();

    const int np = n >> 1;
    const int i = blockIdx.x * BLOCK + threadIdx.x;  // pair index

    float bce = 0.0f, seed_s = 0.0f, smooth_s = 0.0f;

    if (i < np) {
        const float2* e2 = (const float2*)emb;
        float2 a0 = e2[i * 3], a1 = e2[i * 3 + 1], a2 = e2[i * 3 + 2];
        float2 mg = ((const float2*)margins)[i];
        float2 sv = ((const float2*)seed)[i];
        int2 lb = ((const int2*)labels)[i];

        float x[2] = {a0.x, a1.y};
        float y[2] = {a0.y, a2.x};
        float z[2] = {a1.x, a2.y};
        float es[2], a[2] = {0.f, 0.f};
#pragma unroll
        for (int k = 0; k < 2; ++k)
            es[k] = fmaf(x[k], x[k], fmaf(y[k], y[k], z[k] * z[k]));

#pragma unroll 8
        for (int c = 0; c < NCLUS; ++c) {
            float4 pr = s_par[c];
            float w2 = s_w[c];
#pragma unroll
            for (int k = 0; k < 2; ++k) {
                float t = fmaf(pr.x, x[k], fmaf(pr.y, y[k],
                          fmaf(pr.z, z[k], fmaf(w2, es[k], pr.w))));
                float p = EXP2F(t);
                a[k] = fmaf(p, fmaf(p, SPQ2, SPQ1), a[k]);
            }
        }
        bce += a[0] + a[1];

        float mm[2] = {mg.x, mg.y};
        float ss[2] = {sv.x, sv.y};
        int   ll[2] = {lb.x, lb.y};
#pragma unroll
        for (int k = 0; k < 2; ++k) {
            float4 pr = s_par[ll[k]];
            float w2 = s_w[ll[k]];
            float t = fmaf(pr.x, x[k], fmaf(pr.y, y[k],
                      fmaf(pr.z, z[k], fmaf(w2, es[k], pr.w))));
            float p = EXP2F(t);
            bce -= p;
            seed_s += fabsf(p - ss[k]);
            float dg = mm[k] - s_sig[ll[k]];
            smooth_s += dg * dg;
        }
    }
    // odd-n tail
    if ((n & 1) && blockIdx.x == 0 && threadIdx.x == 0) {
        int p = n - 1;
        float ex = emb[p * 3 + 0], ey = emb[p * 3 + 1], ez = emb[p * 3 + 2];
        float esq = fmaf(ex, ex, fmaf(ey, ey, ez * ez));
        int lab = labels[p];
        float pl = 0.0f;
        for (int c = 0; c < NCLUS; ++c) {
            float4 pr = s_par[c];
            float w2 = s_w[c];
            float t = fmaf(pr.x, ex, fmaf(pr.y, ey, fmaf(pr.z, ez, fmaf(w2, esq, pr.w))));
            float p2 = EXP2F(t);
            pl = (c == lab) ? p2 : pl;
            bce = fmaf(p2, fmaf(p2, SPQ2, SPQ1), bce);
        }
        bce -= pl;
        seed_s += fabsf(pl - seed[p]);
        float dg = margins[p] - s_sig[lab];
        smooth_s += dg * dg;
    }

    float r;
    r = block_reduce_f(bce, s_red);
    if (threadIdx.x == 0) pb[blockIdx.x * 3 + 0] = r;
    r = block_reduce_f(seed_s, s_red);
    if (threadIdx.x == 0) pb[blockIdx.x * 3 + 1] = r;
    r = block_reduce_f(smooth_s, s_red);
    if (threadIdx.x == 0) pb[blockIdx.x * 3 + 2] = r;
}

__global__ void finalize_kernel(const float* __restrict__ pb, int nb,
                                float* __restrict__ out, int n) {
    __shared__ float s_red[BLOCK / 64];
    float v0 = 0.f, v1 = 0.f, v2 = 0.f;
    for (int j = threadIdx.x; j < nb; j += BLOCK) {
        v0 += pb[j * 3 + 0];
        v1 += pb[j * 3 + 1];
        v2 += pb[j * 3 + 2];
    }
    float t0 = block_reduce_f(v0, s_red);
    __syncthreads();
    float t1 = block_reduce_f(v1, s_red);
    __syncthreads();
    float t2 = block_reduce_f(v2, s_red);
    if (threadIdx.x == 0) {
        double bce_total = (double)t0 + (double)n * 64.0 * SPQ0;
        out[0] = (float)(bce_total / ((double)NCLUS * (double)n)
                         + (double)t1 / (double)n + (double)t2 / (double)NCLUS);
    }
}

extern "C" void kernel_launch(void* const* d_in, const int* in_sizes, int n_in,
                              void* d_out, int out_size, void* d_ws, size_t ws_size,
                              hipStream_t stream) {
    const float* emb     = (const float*)d_in[0];
    const float* margins = (const float*)d_in[1];
    const float* seed    = (const float*)d_in[2];
    const float* coords  = (const float*)d_in[3];
    const int*   labels  = (const int*)d_in[4];
    int n = in_sizes[4];

    unsigned long long* S8 = (unsigned long long*)d_ws;
    float* pb = (float*)((char*)d_ws + 24576);
    float* out = (float*)d_out;

    int np = n >> 1;
    int grid_main = (np + BLOCK - 1) / BLOCK;
    if (grid_main < 1) grid_main = 1;
    int grid_cs = grid_main < GC ? grid_main : GC;

    init_ws_kernel<<<(NREP * 5 * NCLUS + 255) / 256, 256, 0, stream>>>(S8);
    cluster_sums_kernel<<<grid_cs, BLOCK, 0, stream>>>(coords, margins, labels, n, S8);
    main_loss_kernel<<<grid_main, BLOCK, 0, stream>>>(emb, margins, seed, labels, n, S8, pb);
    finalize_kernel<<<1, BLOCK, 0, stream>>>(pb, grid_main, out, n);
}